// Round 5
// baseline (405.162 us; speedup 1.0000x reference)
//
#include <hip/hip_runtime.h>

#define NN 74240      // nodes
#define NE 593920     // edges
#define DIN 75
#define DD 128
#define NL 3
#define EPS 1e-5f
#define NB 290        // scan blocks: 290*256 == NN
#define NT (NN / 64)  // 1160 row-tiles for k_glayer
#define NREP 64       // replicated BN-sum buffers
#define SROW 136      // LDS agg row stride in shorts (272B: 16B-aligned, bank-spread)

// k_setup block-range dispatch
#define NB_INIT  (NN / 64)                // 1160
#define SB_WPREP NB_INIT                  // 1160
#define NB_WPREP ((NL * 2 * 16384) / 256) // 384
#define SB_HIST  (SB_WPREP + NB_WPREP)    // 1544
#define NB_HIST  (NE / 256)               // 2320
#define SB_PREP  (SB_HIST + NB_HIST)      // 3864
#define NB_SETUP (SB_PREP + 1)            // 3865

typedef __attribute__((ext_vector_type(8))) short short8;   // 8 bf16 = 4 VGPRs (MFMA A/B frag)
typedef __attribute__((ext_vector_type(4))) float f32x4;    // MFMA C/D frag

// fp32 -> bf16 with round-to-nearest-even
static __device__ __forceinline__ unsigned short f2bf(float f) {
    union { float f; unsigned u; } v; v.f = f;
    unsigned u = v.u;
    unsigned r = (u + 0x7fffu + ((u >> 16) & 1u)) >> 16;
    return (unsigned short)r;
}

// bf16 -> fp32 (exact)
static __device__ __forceinline__ float bf2f(unsigned short s) {
    union { unsigned u; float f; } v; v.u = ((unsigned)s) << 16; return v.f;
}

// ---------------- fused setup: init GEMM | weight prepack | degree hist | ab0 -------
// Four mutually independent jobs dispatched by block range so they overlap on-chip
// instead of serializing as 4 launches on one stream.
__global__ __launch_bounds__(256) void k_setup(const float* __restrict__ X,
                                               const float* __restrict__ Wi,
                                               unsigned short* __restrict__ hb,
                                               const float* __restrict__ Wg,
                                               const float* __restrict__ Wr,
                                               unsigned short* __restrict__ wf,
                                               const int* __restrict__ dst,
                                               int* __restrict__ cnt,
                                               float* __restrict__ ab0) {
    __shared__ float sX[64 * DIN];            // 19200 B (init branch only)
    const int tid = threadIdx.x;
    const int b = blockIdx.x;
    if (b < NB_INIT) {
        // ---- init GEMM: h_bf16 = bf16(X @ W_init)  ([NN,75] @ [75,128]) ----
        // 4 waves per 64-row tile; wave w owns cols [w*32, w*32+32) (wave-uniform ->
        // W loads become scalar s_load broadcasts).
        const int r0 = b * 64;
        {   // stage 64 rows of X, float4-vectorized (64*75/4 = 1200 float4)
            const float4* Xv = (const float4*)(X + (size_t)r0 * DIN);
            float4* sv = (float4*)sX;
            #pragma unroll
            for (int i = 0; i < 4; ++i) sv[tid + i * 256] = Xv[tid + i * 256];
            if (tid < 1200 - 1024) sv[tid + 1024] = Xv[tid + 1024];
        }
        __syncthreads();
        const int lane = tid & 63;
        const int cg = __builtin_amdgcn_readfirstlane(tid >> 6) * 32;
        const float* xr = sX + lane * DIN;
        float acc[32];
        #pragma unroll
        for (int j = 0; j < 32; ++j) acc[j] = 0.0f;
        #pragma unroll 5
        for (int k = 0; k < DIN; ++k) {
            const float a = xr[k];
            const float* wk = Wi + k * DD + cg;    // uniform address -> scalar load
            #pragma unroll
            for (int j = 0; j < 32; ++j) acc[j] = fmaf(a, wk[j], acc[j]);
        }
        unsigned short* hrow = hb + (size_t)(r0 + lane) * DD + cg;
        #pragma unroll
        for (int j8 = 0; j8 < 4; ++j8) {
            short8 o;
            #pragma unroll
            for (int j = 0; j < 8; ++j) o[j] = (short)f2bf(acc[j8 * 8 + j]);
            *(short8*)(hrow + j8 * 8) = o;
        }
    } else if (b < SB_HIST) {
        // ---- weight prepack: fp32 [k][n] -> frag-ordered bf16 ----
        // frag flat idx: ((s*8+t)*64 + (q*16+(n&15)))*8 + j, s=k/32 q=(k/8)%4 j=k%8 t=n/16
        const int gt = (b - SB_WPREP) * 256 + tid;
        const int l = gt >> 15;
        const int m = (gt >> 14) & 1;
        const int e = gt & 16383;
        const int k = e >> 7, n = e & 127;
        const float* W = (m == 0 ? Wg : Wr) + l * 16384;
        const float v = W[e];
        const int s = k >> 5, q = (k >> 3) & 3, j = k & 7, t = n >> 4;
        const int ln = (q << 4) | (n & 15);
        const int idx = ((s * 8 + t) * 64 + ln) * 8 + j;
        wf[(l * 2 + m) * 16384 + idx] = f2bf(v);
    } else if (b < SB_PREP) {
        // ---- degree histogram ----
        const int e = (b - SB_HIST) * 256 + tid;
        atomicAdd(&cnt[dst[e]], 1);
    } else {
        // ---- identity affine for layer-0 input ----
        ab0[tid] = (tid < 128) ? 1.0f : 0.0f;
    }
}

// ---------------- CSR build: 3-phase scan -> fill ----------------
__global__ __launch_bounds__(256) void k_scan1(const int* __restrict__ cnt,
                                               int* __restrict__ bsum) {
    const int tid = threadIdx.x;
    int v = cnt[blockIdx.x * 256 + tid];
    #pragma unroll
    for (int off = 1; off < 64; off <<= 1) v += __shfl_xor(v, off, 64);
    __shared__ int ws[4];
    if ((tid & 63) == 0) ws[tid >> 6] = v;
    __syncthreads();
    if (tid == 0) bsum[blockIdx.x] = ws[0] + ws[1] + ws[2] + ws[3];
}

__global__ __launch_bounds__(512) void k_scan2(const int* __restrict__ bsum,
                                               int* __restrict__ boff) {
    __shared__ int s[512];
    const int t = threadIdx.x;
    const int v = (t < NB) ? bsum[t] : 0;
    s[t] = v;
    __syncthreads();
    for (int off = 1; off < 512; off <<= 1) {
        const int u = (t >= off) ? s[t - off] : 0;
        __syncthreads();
        s[t] += u;
        __syncthreads();
    }
    if (t < NB) boff[t] = s[t] - v;   // exclusive
}

__global__ __launch_bounds__(256) void k_scan3(const int* __restrict__ cnt,
                                               const int* __restrict__ boff,
                                               int* __restrict__ rowptr,
                                               int* __restrict__ offs) {
    const int tid = threadIdx.x;
    const int t = blockIdx.x * 256 + tid;
    const int lane = tid & 63;
    const int v = cnt[t];
    int inc = v;
    #pragma unroll
    for (int off = 1; off < 64; off <<= 1) {
        const int u = __shfl_up(inc, off, 64);
        if (lane >= off) inc += u;
    }
    __shared__ int ws[4];
    if (lane == 63) ws[tid >> 6] = inc;
    __syncthreads();
    const int w = tid >> 6;
    int waveoff = 0;
    for (int i = 0; i < 4; ++i) waveoff += (i < w) ? ws[i] : 0;
    const int excl = boff[blockIdx.x] + waveoff + inc - v;
    rowptr[t] = excl;
    offs[t] = excl;
    if (blockIdx.x == NB - 1 && tid == 255) rowptr[NN] = NE;
}

__global__ __launch_bounds__(256) void k_fill(const int* __restrict__ src,
                                              const int* __restrict__ dst,
                                              int* offs, int* __restrict__ col) {
    const int e = blockIdx.x * 256 + threadIdx.x;   // grid == NE
    const int pos = atomicAdd(&offs[dst[e]], 1);
    col[pos] = src[e];
}

// reduce NREP replicated partial-sum buffers -> affine (a,b) for next stage
__global__ __launch_bounds__(128) void k_stats(const float* __restrict__ srep,
                                               const float* __restrict__ gamma,
                                               const float* __restrict__ beta,
                                               float* __restrict__ ab) {
    const int c = threadIdx.x;
    float s = 0.f, q = 0.f;
    for (int r = 0; r < NREP; ++r) {
        s += srep[r * 256 + c];
        q += srep[r * 256 + 128 + c];
    }
    const float invN = 1.0f / (float)NN;
    const float mu = s * invN;
    const float var = q * invN - mu * mu;
    const float a = gamma[c] * rsqrtf(var + EPS);
    ab[c] = a;
    ab[128 + c] = beta[c] - a * mu;
}

// ---------------- fused gather + layer GEMMs (bf16 MFMA, LDS agg tile) -------------
// Block = 64 rows, 4 waves x 16-row M-tiles. Phase 1: each wave gathers ITS 16 rows
// (BN affine folded) into a bf16 LDS tile (row stride 272B: aligned b128, bank-spread)
// -- the agg global round-trip is gone. Phase 2: MFMA as before; A-frags from LDS,
// H-frags from global bf16 hin, B-frags from global frag-ordered wfrag (L2-resident).
__global__ __launch_bounds__(256, 4) void k_glayer(const unsigned short* __restrict__ hin,
                                                   const int* __restrict__ rowptr,
                                                   const int* __restrict__ col,
                                                   const unsigned short* __restrict__ wfrag,
                                                   const float* __restrict__ bg,
                                                   const float* __restrict__ br,
                                                   const float* __restrict__ ab,
                                                   unsigned short* __restrict__ h2b,
                                                   float* __restrict__ sumrep) {
    __shared__ unsigned short sAgg[64 * SROW];   // 17408 B
    __shared__ float sSum[256];
    const int tid = threadIdx.x;
    sSum[tid] = 0.0f;

    const int w = tid >> 6;          // wave 0..3
    const int lane = tid & 63;
    const int l31 = lane & 31;
    const int half = lane >> 5;
    const int f = l31 * 4;           // 4 channels per lane (gather phase)
    const int rbase = blockIdx.x * 64 + w * 16;   // wave's global 16-row base

    // ---- phase 1: gather 16 rows (this wave's own M-tile) ----
    {
        const float4 av = *(const float4*)(ab + f);
        const float4 bv = *(const float4*)(ab + 128 + f);
        int eb = rowptr[rbase];                   // wave-uniform -> scalar
        for (int i = 0; i < 16; ++i) {
            const int ee = rowptr[rbase + i + 1];
            float4 a0 = {0.f,0.f,0.f,0.f}, a1 = {0.f,0.f,0.f,0.f};
            float4 a2 = {0.f,0.f,0.f,0.f}, a3 = {0.f,0.f,0.f,0.f};
            int e = eb + half;
            for (; e + 6 < ee; e += 8) {
                const int c0 = col[e], c1 = col[e + 2], c2 = col[e + 4], c3 = col[e + 6];
                const ushort4 v0 = *(const ushort4*)(hin + (size_t)c0 * DD + f);
                const ushort4 v1 = *(const ushort4*)(hin + (size_t)c1 * DD + f);
                const ushort4 v2 = *(const ushort4*)(hin + (size_t)c2 * DD + f);
                const ushort4 v3 = *(const ushort4*)(hin + (size_t)c3 * DD + f);
                a0.x += bf2f(v0.x); a0.y += bf2f(v0.y); a0.z += bf2f(v0.z); a0.w += bf2f(v0.w);
                a1.x += bf2f(v1.x); a1.y += bf2f(v1.y); a1.z += bf2f(v1.z); a1.w += bf2f(v1.w);
                a2.x += bf2f(v2.x); a2.y += bf2f(v2.y); a2.z += bf2f(v2.z); a2.w += bf2f(v2.w);
                a3.x += bf2f(v3.x); a3.y += bf2f(v3.y); a3.z += bf2f(v3.z); a3.w += bf2f(v3.w);
            }
            for (; e < ee; e += 2) {
                const int c = col[e];
                const ushort4 v = *(const ushort4*)(hin + (size_t)c * DD + f);
                a0.x += bf2f(v.x); a0.y += bf2f(v.y); a0.z += bf2f(v.z); a0.w += bf2f(v.w);
            }
            float4 s;
            s.x = (a0.x + a1.x) + (a2.x + a3.x);
            s.y = (a0.y + a1.y) + (a2.y + a3.y);
            s.z = (a0.z + a1.z) + (a2.z + a3.z);
            s.w = (a0.w + a1.w) + (a2.w + a3.w);
            s.x += __shfl_xor(s.x, 32, 64);
            s.y += __shfl_xor(s.y, 32, 64);
            s.z += __shfl_xor(s.z, 32, 64);
            s.w += __shfl_xor(s.w, 32, 64);
            if (half == 0) {
                const float deg = (float)(ee - eb);
                ushort4 o;
                o.x = f2bf(fmaf(av.x, s.x, deg * bv.x));
                o.y = f2bf(fmaf(av.y, s.y, deg * bv.y));
                o.z = f2bf(fmaf(av.z, s.z, deg * bv.z));
                o.w = f2bf(fmaf(av.w, s.w, deg * bv.w));
                *(ushort4*)&sAgg[(w * 16 + i) * SROW + f] = o;
            }
            eb = ee;
        }
    }
    __syncthreads();   // sAgg + sSum visible (waves only read own rows, but be safe)

    // ---- phase 2: dual GEMM ----
    const int ln15 = lane & 15;
    const int q = lane >> 4;
    const int arow = rbase + ln15;       // global row for H frag
    const int lrow = w * 16 + ln15;      // LDS row for A frag

    const short8* __restrict__ wgf = (const short8*)wfrag;   // 2048 short8 (frag-ordered Wg)
    const short8* __restrict__ wrf = wgf + 2048;             // frag-ordered Wr

    f32x4 accg[8], accr[8];
    #pragma unroll
    for (int t = 0; t < 8; ++t) {
        accg[t] = (f32x4){0.f, 0.f, 0.f, 0.f};
        accr[t] = (f32x4){0.f, 0.f, 0.f, 0.f};
    }

    #pragma unroll
    for (int s = 0; s < 4; ++s) {
        const int kk = s * 32 + q * 8;
        const short8 af = *(const short8*)&sAgg[lrow * SROW + kk];  // frag-ready (affine'd)
        const short8 hr = *(const short8*)(hin + (size_t)arow * DD + kk);
        const float4 av0 = *(const float4*)(ab + kk);
        const float4 av1 = *(const float4*)(ab + kk + 4);
        const float4 bv0 = *(const float4*)(ab + 128 + kk);
        const float4 bv1 = *(const float4*)(ab + 128 + kk + 4);
        short8 hf;
        hf[0] = (short)f2bf(fmaf(av0.x, bf2f((unsigned short)hr[0]), bv0.x));
        hf[1] = (short)f2bf(fmaf(av0.y, bf2f((unsigned short)hr[1]), bv0.y));
        hf[2] = (short)f2bf(fmaf(av0.z, bf2f((unsigned short)hr[2]), bv0.z));
        hf[3] = (short)f2bf(fmaf(av0.w, bf2f((unsigned short)hr[3]), bv0.w));
        hf[4] = (short)f2bf(fmaf(av1.x, bf2f((unsigned short)hr[4]), bv1.x));
        hf[5] = (short)f2bf(fmaf(av1.y, bf2f((unsigned short)hr[5]), bv1.y));
        hf[6] = (short)f2bf(fmaf(av1.z, bf2f((unsigned short)hr[6]), bv1.z));
        hf[7] = (short)f2bf(fmaf(av1.w, bf2f((unsigned short)hr[7]), bv1.w));
        const int fb = s * 512;   // frag base for this k-step, in short8 units
        #pragma unroll
        for (int t = 0; t < 8; ++t) {
            const short8 bgf = wgf[fb + t * 64 + lane];
            const short8 brf = wrf[fb + t * 64 + lane];
            accg[t] = __builtin_amdgcn_mfma_f32_16x16x32_bf16(af, bgf, accg[t], 0, 0, 0);
            accr[t] = __builtin_amdgcn_mfma_f32_16x16x32_bf16(hf, brf, accr[t], 0, 0, 0);
        }
    }

    // epilogue: bias + relu + add, store bf16 h2, fused fp32 BN partial sums
    #pragma unroll
    for (int t = 0; t < 8; ++t) {
        const int c = t * 16 + ln15;
        const float bgc = bg[c];
        const float brc = br[c];
        float sv = 0.f, qv = 0.f;
        #pragma unroll
        for (int r = 0; r < 4; ++r) {
            const int row = rbase + q * 4 + r;
            const float v = fmaxf(accg[t][r] + bgc, 0.f) + fmaxf(accr[t][r] + brc, 0.f);
            h2b[(size_t)row * DD + c] = f2bf(v);
            sv += v; qv += v * v;
        }
        sv += __shfl_xor(sv, 16, 64); sv += __shfl_xor(sv, 32, 64);
        qv += __shfl_xor(qv, 16, 64); qv += __shfl_xor(qv, 32, 64);
        if (q == 0) {
            atomicAdd(&sSum[c], sv);
            atomicAdd(&sSum[128 + c], qv);
        }
    }
    __syncthreads();
    atomicAdd(&sumrep[(blockIdx.x & (NREP - 1)) * 256 + tid], sSum[tid]);
}

// ---------------- BatchNorm normalize (final layer): pure affine, bf16 in fp32 out --
__global__ __launch_bounds__(256) void k_bn(const unsigned short* __restrict__ h2b,
                                            const float* __restrict__ ab,
                                            float* __restrict__ out) {
    const int t = blockIdx.x * 256 + threadIdx.x;  // NN*32 threads
    const size_t base = (size_t)t * 4;
    const int c = (int)(base & 127);
    const ushort4 v = *(const ushort4*)(h2b + base);
    const float4 a = *(const float4*)(ab + c);
    const float4 b = *(const float4*)(ab + 128 + c);
    float4 o;
    o.x = fmaf(a.x, bf2f(v.x), b.x);
    o.y = fmaf(a.y, bf2f(v.y), b.y);
    o.z = fmaf(a.z, bf2f(v.z), b.z);
    o.w = fmaf(a.w, bf2f(v.w), b.w);
    *(float4*)(out + base) = o;
}

extern "C" void kernel_launch(void* const* d_in, const int* in_sizes, int n_in,
                              void* d_out, int out_size, void* d_ws, size_t ws_size,
                              hipStream_t stream) {
    const float* X     = (const float*)d_in[0];
    const int*   src   = (const int*)d_in[1];
    const int*   dst   = (const int*)d_in[2];
    const float* Wi    = (const float*)d_in[3];
    const float* Wg    = (const float*)d_in[4];
    const float* bg    = (const float*)d_in[5];
    const float* Wr    = (const float*)d_in[6];
    const float* br    = (const float*)d_in[7];
    const float* gamma = (const float*)d_in[8];
    const float* beta  = (const float*)d_in[9];
    float* out = (float*)d_out;

    unsigned short* hA   = (unsigned short*)d_ws;         // [NN*DD] bf16
    unsigned short* hB   = hA + (size_t)NN * DD;          // [NN*DD] bf16
    float* sumrep = (float*)(hB + (size_t)NN * DD);       // [NL*NREP*256]
    int* cnt      = (int*)(sumrep + NL * NREP * 256);     // [NN] (adjacent: 1 memset)
    int* offs     = cnt + NN;                             // [NN]
    float* abv    = (float*)(offs + NN);                  // [(NL+1)*2*DD] a/b per stage
    unsigned short* wfrag = (unsigned short*)(abv + (NL + 1) * 2 * DD);  // bf16 frags
    int* rowptr = (int*)(wfrag + NL * 2 * 16384);         // [NN+1]
    int* col    = rowptr + NN + 1;                        // [NE]
    int* bsum   = col + NE;                               // [NB]
    int* boff   = bsum + NB;                              // [NB]

    // one memset: sumrep (floats) + cnt (ints), both zero-byte patterns, adjacent
    hipMemsetAsync(sumrep, 0, (size_t)(NL * NREP * 256 + NN) * sizeof(float), stream);

    k_setup<<<NB_SETUP, 256, 0, stream>>>(X, Wi, hA, Wg, Wr, wfrag, dst, cnt, abv);
    k_scan1<<<NB, 256, 0, stream>>>(cnt, bsum);
    k_scan2<<<1, 512, 0, stream>>>(bsum, boff);
    k_scan3<<<NB, 256, 0, stream>>>(cnt, boff, rowptr, offs);
    k_fill<<<NE / 256, 256, 0, stream>>>(src, dst, offs, col);

    // bf16 activation ping-pong: hA -> hB -> hA -> hB; k_bn reads final hB
    const unsigned short* hcur = hA;
    unsigned short* h2bufs[NL] = { hB, hA, hB };
    for (int l = 0; l < NL; ++l) {
        const float* abl = abv + l * 2 * DD;
        unsigned short* h2 = h2bufs[l];
        k_glayer<<<NT, 256, 0, stream>>>(hcur, rowptr, col,
                                         wfrag + l * 2 * 16384,
                                         bg + l * DD, br + l * DD,
                                         abl, h2, sumrep + (size_t)l * NREP * 256);
        k_stats<<<1, 128, 0, stream>>>(sumrep + (size_t)l * NREP * 256, gamma + l * DD,
                                       beta + l * DD, abv + (l + 1) * 2 * DD);
        if (l == NL - 1) {
            k_bn<<<(NN * 32) / 256, 256, 0, stream>>>(h2, abv + NL * 2 * DD, out);
        }
        hcur = h2;
    }
}

// Round 6
// 321.785 us; speedup vs baseline: 1.2591x; 1.2591x over previous
//
#include <hip/hip_runtime.h>

#define NN 74240      // nodes
#define NE 593920     // edges
#define DIN 75
#define DD 128
#define NL 3
#define EPS 1e-5f
#define NB 290        // scan blocks: 290*256 == NN
#define NT (NN / 64)  // 1160 row-tiles for k_layer
#define NREP 64       // replicated BN-sum buffers

// k_setup block-range dispatch
#define NB_INIT  (NN / 64)                // 1160
#define SB_WPREP NB_INIT                  // 1160
#define NB_WPREP ((NL * 2 * 16384) / 256) // 384
#define SB_HIST  (SB_WPREP + NB_WPREP)    // 1544
#define NB_HIST  (NE / 256)               // 2320
#define SB_PREP  (SB_HIST + NB_HIST)      // 3864
#define NB_SETUP (SB_PREP + 1)            // 3865

typedef __attribute__((ext_vector_type(8))) short short8;   // 8 bf16 = 4 VGPRs (MFMA A/B frag)
typedef __attribute__((ext_vector_type(4))) float f32x4;    // MFMA C/D frag

// fp32 -> bf16 with round-to-nearest-even
static __device__ __forceinline__ unsigned short f2bf(float f) {
    union { float f; unsigned u; } v; v.f = f;
    unsigned u = v.u;
    unsigned r = (u + 0x7fffu + ((u >> 16) & 1u)) >> 16;
    return (unsigned short)r;
}

// bf16 -> fp32 (exact)
static __device__ __forceinline__ float bf2f(unsigned short s) {
    union { unsigned u; float f; } v; v.u = ((unsigned)s) << 16; return v.f;
}

// ---------------- fused setup: init GEMM | weight prepack | degree hist | ab0 -------
// Four mutually independent jobs dispatched by block range so they overlap on-chip
// instead of serializing as 4 launches on one stream.
__global__ __launch_bounds__(256) void k_setup(const float* __restrict__ X,
                                               const float* __restrict__ Wi,
                                               unsigned short* __restrict__ hb,
                                               const float* __restrict__ Wg,
                                               const float* __restrict__ Wr,
                                               unsigned short* __restrict__ wf,
                                               const int* __restrict__ dst,
                                               int* __restrict__ cnt,
                                               float* __restrict__ ab0) {
    __shared__ float sX[64 * DIN];            // 19200 B (init branch only)
    const int tid = threadIdx.x;
    const int b = blockIdx.x;
    if (b < NB_INIT) {
        // ---- init GEMM: h_bf16 = bf16(X @ W_init)  ([NN,75] @ [75,128]) ----
        // 4 waves per 64-row tile; wave w owns cols [w*32, w*32+32) (wave-uniform ->
        // W loads become scalar s_load broadcasts).
        const int r0 = b * 64;
        {   // stage 64 rows of X, float4-vectorized (64*75/4 = 1200 float4)
            const float4* Xv = (const float4*)(X + (size_t)r0 * DIN);
            float4* sv = (float4*)sX;
            #pragma unroll
            for (int i = 0; i < 4; ++i) sv[tid + i * 256] = Xv[tid + i * 256];
            if (tid < 1200 - 1024) sv[tid + 1024] = Xv[tid + 1024];
        }
        __syncthreads();
        const int lane = tid & 63;
        const int cg = __builtin_amdgcn_readfirstlane(tid >> 6) * 32;
        const float* xr = sX + lane * DIN;
        float acc[32];
        #pragma unroll
        for (int j = 0; j < 32; ++j) acc[j] = 0.0f;
        #pragma unroll 5
        for (int k = 0; k < DIN; ++k) {
            const float a = xr[k];
            const float* wk = Wi + k * DD + cg;    // uniform address -> scalar load
            #pragma unroll
            for (int j = 0; j < 32; ++j) acc[j] = fmaf(a, wk[j], acc[j]);
        }
        unsigned short* hrow = hb + (size_t)(r0 + lane) * DD + cg;
        #pragma unroll
        for (int j8 = 0; j8 < 4; ++j8) {
            short8 o;
            #pragma unroll
            for (int j = 0; j < 8; ++j) o[j] = (short)f2bf(acc[j8 * 8 + j]);
            *(short8*)(hrow + j8 * 8) = o;
        }
    } else if (b < SB_HIST) {
        // ---- weight prepack: fp32 [k][n] -> frag-ordered bf16 ----
        // frag flat idx: ((s*8+t)*64 + (q*16+(n&15)))*8 + j, s=k/32 q=(k/8)%4 j=k%8 t=n/16
        const int gt = (b - SB_WPREP) * 256 + tid;
        const int l = gt >> 15;
        const int m = (gt >> 14) & 1;
        const int e = gt & 16383;
        const int k = e >> 7, n = e & 127;
        const float* W = (m == 0 ? Wg : Wr) + l * 16384;
        const float v = W[e];
        const int s = k >> 5, q = (k >> 3) & 3, j = k & 7, t = n >> 4;
        const int ln = (q << 4) | (n & 15);
        const int idx = ((s * 8 + t) * 64 + ln) * 8 + j;
        wf[(l * 2 + m) * 16384 + idx] = f2bf(v);
    } else if (b < SB_PREP) {
        // ---- degree histogram ----
        const int e = (b - SB_HIST) * 256 + tid;
        atomicAdd(&cnt[dst[e]], 1);
    } else {
        // ---- identity affine for layer-0 input ----
        ab0[tid] = (tid < 128) ? 1.0f : 0.0f;
    }
}

// ---------------- CSR build: 3-phase scan -> fill ----------------
__global__ __launch_bounds__(256) void k_scan1(const int* __restrict__ cnt,
                                               int* __restrict__ bsum) {
    const int tid = threadIdx.x;
    int v = cnt[blockIdx.x * 256 + tid];
    #pragma unroll
    for (int off = 1; off < 64; off <<= 1) v += __shfl_xor(v, off, 64);
    __shared__ int ws[4];
    if ((tid & 63) == 0) ws[tid >> 6] = v;
    __syncthreads();
    if (tid == 0) bsum[blockIdx.x] = ws[0] + ws[1] + ws[2] + ws[3];
}

__global__ __launch_bounds__(512) void k_scan2(const int* __restrict__ bsum,
                                               int* __restrict__ boff) {
    __shared__ int s[512];
    const int t = threadIdx.x;
    const int v = (t < NB) ? bsum[t] : 0;
    s[t] = v;
    __syncthreads();
    for (int off = 1; off < 512; off <<= 1) {
        const int u = (t >= off) ? s[t - off] : 0;
        __syncthreads();
        s[t] += u;
        __syncthreads();
    }
    if (t < NB) boff[t] = s[t] - v;   // exclusive
}

__global__ __launch_bounds__(256) void k_scan3(const int* __restrict__ cnt,
                                               const int* __restrict__ boff,
                                               int* __restrict__ rowptr,
                                               int* __restrict__ offs) {
    const int tid = threadIdx.x;
    const int t = blockIdx.x * 256 + tid;
    const int lane = tid & 63;
    const int v = cnt[t];
    int inc = v;
    #pragma unroll
    for (int off = 1; off < 64; off <<= 1) {
        const int u = __shfl_up(inc, off, 64);
        if (lane >= off) inc += u;
    }
    __shared__ int ws[4];
    if (lane == 63) ws[tid >> 6] = inc;
    __syncthreads();
    const int w = tid >> 6;
    int waveoff = 0;
    for (int i = 0; i < 4; ++i) waveoff += (i < w) ? ws[i] : 0;
    const int excl = boff[blockIdx.x] + waveoff + inc - v;
    rowptr[t] = excl;
    offs[t] = excl;
    if (blockIdx.x == NB - 1 && tid == 255) rowptr[NN] = NE;
}

__global__ __launch_bounds__(256) void k_fill(const int* __restrict__ src,
                                              const int* __restrict__ dst,
                                              int* offs, int* __restrict__ col) {
    const int e = blockIdx.x * 256 + threadIdx.x;   // grid == NE
    const int pos = atomicAdd(&offs[dst[e]], 1);
    col[pos] = src[e];
}

// reduce NREP replicated partial-sum buffers -> affine (a,b) for next stage
__global__ __launch_bounds__(128) void k_stats(const float* __restrict__ srep,
                                               const float* __restrict__ gamma,
                                               const float* __restrict__ beta,
                                               float* __restrict__ ab) {
    const int c = threadIdx.x;
    float s = 0.f, q = 0.f;
    for (int r = 0; r < NREP; ++r) {
        s += srep[r * 256 + c];
        q += srep[r * 256 + 128 + c];
    }
    const float invN = 1.0f / (float)NN;
    const float mu = s * invN;
    const float var = q * invN - mu * mu;
    const float a = gamma[c] * rsqrtf(var + EPS);
    ab[c] = a;
    ab[128 + c] = beta[c] - a * mu;
}

// ---------------- gather (BN folded): aggb[row] = bf16(a * sum_e hb[col[e]] + deg*b) --
// One row per wave, NN/4 blocks: thousands of rows in flight hide random-gather
// latency (the round-5 fused version serialized 16 rows/wave and lost 3x -- keep
// this shape). hb rows are 256B bf16. Output row-major bf16 with affine applied
// = ready-made MFMA A-fragments for k_layer.
__global__ __launch_bounds__(256) void k_gather(const unsigned short* __restrict__ hb,
                                                const int* __restrict__ rowptr,
                                                const int* __restrict__ col,
                                                const float* __restrict__ ab,
                                                unsigned short* __restrict__ aggb) {
    const int wave = threadIdx.x >> 6;
    const int lane = threadIdx.x & 63;
    const int row = blockIdx.x * 4 + wave;   // grid = NN/4
    const int eb = rowptr[row];
    const int ee = rowptr[row + 1];
    const int half = lane >> 5;
    const int f = (lane & 31) * 4;           // 4 channels per lane
    float4 a0 = {0.f,0.f,0.f,0.f}, a1 = {0.f,0.f,0.f,0.f};
    float4 a2 = {0.f,0.f,0.f,0.f}, a3 = {0.f,0.f,0.f,0.f};
    int e = eb + half;
    for (; e + 6 < ee; e += 8) {
        const int c0 = col[e], c1 = col[e + 2], c2 = col[e + 4], c3 = col[e + 6];
        const ushort4 v0 = *(const ushort4*)(hb + (size_t)c0 * DD + f);
        const ushort4 v1 = *(const ushort4*)(hb + (size_t)c1 * DD + f);
        const ushort4 v2 = *(const ushort4*)(hb + (size_t)c2 * DD + f);
        const ushort4 v3 = *(const ushort4*)(hb + (size_t)c3 * DD + f);
        a0.x += bf2f(v0.x); a0.y += bf2f(v0.y); a0.z += bf2f(v0.z); a0.w += bf2f(v0.w);
        a1.x += bf2f(v1.x); a1.y += bf2f(v1.y); a1.z += bf2f(v1.z); a1.w += bf2f(v1.w);
        a2.x += bf2f(v2.x); a2.y += bf2f(v2.y); a2.z += bf2f(v2.z); a2.w += bf2f(v2.w);
        a3.x += bf2f(v3.x); a3.y += bf2f(v3.y); a3.z += bf2f(v3.z); a3.w += bf2f(v3.w);
    }
    for (; e < ee; e += 2) {
        const int c = col[e];
        const ushort4 v = *(const ushort4*)(hb + (size_t)c * DD + f);
        a0.x += bf2f(v.x); a0.y += bf2f(v.y); a0.z += bf2f(v.z); a0.w += bf2f(v.w);
    }
    float4 s;
    s.x = (a0.x + a1.x) + (a2.x + a3.x);
    s.y = (a0.y + a1.y) + (a2.y + a3.y);
    s.z = (a0.z + a1.z) + (a2.z + a3.z);
    s.w = (a0.w + a1.w) + (a2.w + a3.w);
    s.x += __shfl_xor(s.x, 32, 64);
    s.y += __shfl_xor(s.y, 32, 64);
    s.z += __shfl_xor(s.z, 32, 64);
    s.w += __shfl_xor(s.w, 32, 64);
    if (half == 0) {
        const float deg = (float)(ee - eb);
        const float4 av = *(const float4*)(ab + f);
        const float4 bv = *(const float4*)(ab + 128 + f);
        ushort4 o;
        o.x = f2bf(fmaf(av.x, s.x, deg * bv.x));
        o.y = f2bf(fmaf(av.y, s.y, deg * bv.y));
        o.z = f2bf(fmaf(av.z, s.z, deg * bv.z));
        o.w = f2bf(fmaf(av.w, s.w, deg * bv.w));
        *(ushort4*)(aggb + (size_t)row * DD + f) = o;
    }
}

// ---------------- fused layer GEMMs via bf16 MFMA (no weight LDS, bf16 I/O) --------
// One 64-row tile per block. B-frags read directly from global frag-ordered wfrag
// (64KB/layer, L2-resident). A-frags = direct short8 loads from aggb (affine already
// applied by k_gather). H-frags = bf16 hin + affine. Output h2 bf16 (fp32 BN sums).
__global__ __launch_bounds__(256, 4) void k_layer(const unsigned short* __restrict__ hin,
                                                  const unsigned short* __restrict__ aggb,
                                                  const unsigned short* __restrict__ wfrag,
                                                  const float* __restrict__ bg,
                                                  const float* __restrict__ br,
                                                  const float* __restrict__ ab,
                                                  unsigned short* __restrict__ h2b,
                                                  float* __restrict__ sumrep) {
    __shared__ float sSum[256];
    const int tid = threadIdx.x;
    sSum[tid] = 0.0f;
    __syncthreads();

    const int w = tid >> 6;          // wave 0..3
    const int lane = tid & 63;
    const int ln15 = lane & 15;
    const int q = lane >> 4;
    const int r0 = blockIdx.x * 64 + w * 16;   // wave's 16-row M-tile base
    const int arow = r0 + ln15;                // row this lane's A/H frag holds

    const short8* __restrict__ wgf = (const short8*)wfrag;   // 2048 short8 (frag-ordered Wg)
    const short8* __restrict__ wrf = wgf + 2048;             // frag-ordered Wr

    f32x4 accg[8], accr[8];
    #pragma unroll
    for (int t = 0; t < 8; ++t) {
        accg[t] = (f32x4){0.f, 0.f, 0.f, 0.f};
        accr[t] = (f32x4){0.f, 0.f, 0.f, 0.f};
    }

    #pragma unroll
    for (int s = 0; s < 4; ++s) {
        const int kk = s * 32 + q * 8;
        const short8 af = *(const short8*)(aggb + (size_t)arow * DD + kk);  // frag-ready
        const short8 hr = *(const short8*)(hin + (size_t)arow * DD + kk);
        const float4 av0 = *(const float4*)(ab + kk);
        const float4 av1 = *(const float4*)(ab + kk + 4);
        const float4 bv0 = *(const float4*)(ab + 128 + kk);
        const float4 bv1 = *(const float4*)(ab + 128 + kk + 4);
        short8 hf;
        hf[0] = (short)f2bf(fmaf(av0.x, bf2f((unsigned short)hr[0]), bv0.x));
        hf[1] = (short)f2bf(fmaf(av0.y, bf2f((unsigned short)hr[1]), bv0.y));
        hf[2] = (short)f2bf(fmaf(av0.z, bf2f((unsigned short)hr[2]), bv0.z));
        hf[3] = (short)f2bf(fmaf(av0.w, bf2f((unsigned short)hr[3]), bv0.w));
        hf[4] = (short)f2bf(fmaf(av1.x, bf2f((unsigned short)hr[4]), bv1.x));
        hf[5] = (short)f2bf(fmaf(av1.y, bf2f((unsigned short)hr[5]), bv1.y));
        hf[6] = (short)f2bf(fmaf(av1.z, bf2f((unsigned short)hr[6]), bv1.z));
        hf[7] = (short)f2bf(fmaf(av1.w, bf2f((unsigned short)hr[7]), bv1.w));
        const int fb = s * 512;   // frag base for this k-step, in short8 units
        #pragma unroll
        for (int t = 0; t < 8; ++t) {
            const short8 bgf = wgf[fb + t * 64 + lane];
            const short8 brf = wrf[fb + t * 64 + lane];
            accg[t] = __builtin_amdgcn_mfma_f32_16x16x32_bf16(af, bgf, accg[t], 0, 0, 0);
            accr[t] = __builtin_amdgcn_mfma_f32_16x16x32_bf16(hf, brf, accr[t], 0, 0, 0);
        }
    }

    // epilogue: bias + relu + add, store bf16 h2, fused fp32 BN partial sums
    #pragma unroll
    for (int t = 0; t < 8; ++t) {
        const int c = t * 16 + ln15;
        const float bgc = bg[c];
        const float brc = br[c];
        float sv = 0.f, qv = 0.f;
        #pragma unroll
        for (int r = 0; r < 4; ++r) {
            const int row = r0 + q * 4 + r;
            const float v = fmaxf(accg[t][r] + bgc, 0.f) + fmaxf(accr[t][r] + brc, 0.f);
            h2b[(size_t)row * DD + c] = f2bf(v);
            sv += v; qv += v * v;
        }
        sv += __shfl_xor(sv, 16, 64); sv += __shfl_xor(sv, 32, 64);
        qv += __shfl_xor(qv, 16, 64); qv += __shfl_xor(qv, 32, 64);
        if (q == 0) {
            atomicAdd(&sSum[c], sv);
            atomicAdd(&sSum[128 + c], qv);
        }
    }
    __syncthreads();
    atomicAdd(&sumrep[(blockIdx.x & (NREP - 1)) * 256 + tid], sSum[tid]);
}

// ---------------- BatchNorm normalize (final layer): pure affine, bf16 in fp32 out --
__global__ __launch_bounds__(256) void k_bn(const unsigned short* __restrict__ h2b,
                                            const float* __restrict__ ab,
                                            float* __restrict__ out) {
    const int t = blockIdx.x * 256 + threadIdx.x;  // NN*32 threads
    const size_t base = (size_t)t * 4;
    const int c = (int)(base & 127);
    const ushort4 v = *(const ushort4*)(h2b + base);
    const float4 a = *(const float4*)(ab + c);
    const float4 b = *(const float4*)(ab + 128 + c);
    float4 o;
    o.x = fmaf(a.x, bf2f(v.x), b.x);
    o.y = fmaf(a.y, bf2f(v.y), b.y);
    o.z = fmaf(a.z, bf2f(v.z), b.z);
    o.w = fmaf(a.w, bf2f(v.w), b.w);
    *(float4*)(out + base) = o;
}

extern "C" void kernel_launch(void* const* d_in, const int* in_sizes, int n_in,
                              void* d_out, int out_size, void* d_ws, size_t ws_size,
                              hipStream_t stream) {
    const float* X     = (const float*)d_in[0];
    const int*   src   = (const int*)d_in[1];
    const int*   dst   = (const int*)d_in[2];
    const float* Wi    = (const float*)d_in[3];
    const float* Wg    = (const float*)d_in[4];
    const float* bg    = (const float*)d_in[5];
    const float* Wr    = (const float*)d_in[6];
    const float* br    = (const float*)d_in[7];
    const float* gamma = (const float*)d_in[8];
    const float* beta  = (const float*)d_in[9];
    float* out = (float*)d_out;

    unsigned short* hA   = (unsigned short*)d_ws;         // [NN*DD] bf16
    unsigned short* hB   = hA + (size_t)NN * DD;          // [NN*DD] bf16
    unsigned short* aggb = hB + (size_t)NN * DD;          // [NN*DD] bf16
    float* sumrep = (float*)(aggb + (size_t)NN * DD);     // [NL*NREP*256]
    int* cnt      = (int*)(sumrep + NL * NREP * 256);     // [NN] (adjacent: 1 memset)
    int* offs     = cnt + NN;                             // [NN]
    float* abv    = (float*)(offs + NN);                  // [(NL+1)*2*DD] a/b per stage
    unsigned short* wfrag = (unsigned short*)(abv + (NL + 1) * 2 * DD);  // bf16 frags
    int* rowptr = (int*)(wfrag + NL * 2 * 16384);         // [NN+1]
    int* col    = rowptr + NN + 1;                        // [NE]
    int* bsum   = col + NE;                               // [NB]
    int* boff   = bsum + NB;                              // [NB]

    // one memset: sumrep (floats) + cnt (ints), both zero-byte patterns, adjacent
    hipMemsetAsync(sumrep, 0, (size_t)(NL * NREP * 256 + NN) * sizeof(float), stream);

    k_setup<<<NB_SETUP, 256, 0, stream>>>(X, Wi, hA, Wg, Wr, wfrag, dst, cnt, abv);
    k_scan1<<<NB, 256, 0, stream>>>(cnt, bsum);
    k_scan2<<<1, 512, 0, stream>>>(bsum, boff);
    k_scan3<<<NB, 256, 0, stream>>>(cnt, boff, rowptr, offs);
    k_fill<<<NE / 256, 256, 0, stream>>>(src, dst, offs, col);

    // bf16 activation ping-pong: hA -> hB -> hA -> hB; k_bn reads final hB
    const unsigned short* hcur = hA;
    unsigned short* h2bufs[NL] = { hB, hA, hB };
    for (int l = 0; l < NL; ++l) {
        const float* abl = abv + l * 2 * DD;
        unsigned short* h2 = h2bufs[l];
        k_gather<<<NN / 4, 256, 0, stream>>>(hcur, rowptr, col, abl, aggb);
        k_layer<<<NT, 256, 0, stream>>>(hcur, aggb,
                                        wfrag + l * 2 * 16384,
                                        bg + l * DD, br + l * DD,
                                        abl, h2, sumrep + (size_t)l * NREP * 256);
        k_stats<<<1, 128, 0, stream>>>(sumrep + (size_t)l * NREP * 256, gamma + l * DD,
                                       beta + l * DD, abv + (l + 1) * 2 * DD);
        if (l == NL - 1) {
            k_bn<<<(NN * 32) / 256, 256, 0, stream>>>(h2, abv + NL * 2 * DD, out);
        }
        hcur = h2;
    }
}